// Round 14
// baseline (167.731 us; speedup 1.0000x reference)
//
#include <hip/hip_runtime.h>
#include <hip/hip_bf16.h>

// MahalanobisDistanceLayer: B=8192, D=64.
// q = E @ E^T with E = (a-b) * rsqrt(var_per_feature(concat(a,b)+eps));
// out[i] = sum_j (q<0 ? 0 : sqrt(q)) + B*EPS_OUT for (anchor,positive), (anchor,negative).
//
// Split-bf16: E = Ehi + Elo -> K=192 bf16 GEMM on MFMA. Symmetric tile-pair scheme
// halves FLOPs: unordered 128-row tile pair {ib,(ib+s)&63} done once (s<=32, s=32 only
// ib<32); off-diag adds row-sums to ib-rows AND col-sums to jb-rows.
// 3 dispatches: stats(256-blk partials, no memset) -> prep(coalesced reduce+EHL) -> mdist.
// mdist: 512 blocks (2/CU), FULL 32KB B tile staged per outer step -> one barrier per
// 96 MFMAs (R5 cadence; R8 paid a barrier per 48). 2 waves/SIMD is the real occupancy
// (AGPR acc pushes total regs past 128 -- R13 lesson); do NOT force more (R7/R12 spill).

typedef short bf16x8 __attribute__((ext_vector_type(8)));
typedef unsigned short u16x8 __attribute__((ext_vector_type(8)));
typedef float f32x4 __attribute__((ext_vector_type(4)));

#define BROWS 8192
#define DFEAT 64
#define NCO   16384
#define EPS_IN  1e-4f
#define EPS_OUT 1e-6f
#define NPART 256

// ---- workspace layout (floats) ----
// [0, 98304)        : part[b][v] partials (256 blocks x 384), non-atomic, b-major
// [98560, +1M fl)   : EHL, 2 pairs x 8192 rows x 128 bf16 (row=[hi|lo], 256B),
//                     16B-chunk index XOR-swizzled by (row&7)
#define WS_EHL_F  98560
#define EHL_PAIR_USHORTS ((size_t)BROWS * 128)

static __device__ inline unsigned short f2bf_rne(float x) {
  unsigned u = __float_as_uint(x);
  unsigned r = (u + 0x7FFF + ((u >> 16) & 1)) >> 16;
  return (unsigned short)r;
}
static __device__ inline float bf2f(unsigned short s) {
  return __uint_as_float(((unsigned)s) << 16);
}

#define GLOAD(gsrc, ldst)                                                  \
  __builtin_amdgcn_global_load_lds(                                        \
      (const __attribute__((address_space(1))) void*)(gsrc),               \
      (__attribute__((address_space(3))) void*)(ldst), 16, 0, 0)

// ---------------------------------------------------------------------------
// Kernel A: per-block stats partials, NON-atomic (no zero-init needed).
// 256 blocks x 256 threads; 2 float4/thread/array.
__global__ __launch_bounds__(256) void stats_kernel(
    const float* __restrict__ a, const float* __restrict__ p,
    const float* __restrict__ n, float* __restrict__ part) {
  __shared__ float acc[384];
  int tid = threadIdx.x;
  int bid = blockIdx.x;
  for (int v = tid; v < 384; v += 256) acc[v] = 0.f;
  __syncthreads();
  const float4* A4 = (const float4*)a;
  const float4* P4 = (const float4*)p;
  const float4* N4 = (const float4*)n;
  size_t base = (size_t)bid * 512 + tid;
  float s[3][4] = {}, q[3][4] = {};
  #pragma unroll
  for (int k = 0; k < 2; ++k) {
    size_t idx = base + k * 256;
    float4 va = A4[idx], vp = P4[idx], vn = N4[idx];
    float ea[4] = {va.x, va.y, va.z, va.w};
    float ep[4] = {vp.x, vp.y, vp.z, vp.w};
    float en[4] = {vn.x, vn.y, vn.z, vn.w};
    #pragma unroll
    for (int f = 0; f < 4; ++f) {
      float x0 = ea[f] + EPS_IN; s[0][f] += x0; q[0][f] += x0 * x0;
      float x1 = ep[f] + EPS_IN; s[1][f] += x1; q[1][f] += x1 * x1;
      float x2 = en[f] + EPS_IN; s[2][f] += x2; q[2][f] += x2 * x2;
    }
  }
  // lanes t, t^16, t^32, t^48 share feature group d0 = 4*(t&15)
  #pragma unroll
  for (int g = 0; g < 3; ++g)
    #pragma unroll
    for (int f = 0; f < 4; ++f) {
      float vs = s[g][f], vq = q[g][f];
      vs += __shfl_xor(vs, 16); vs += __shfl_xor(vs, 32);
      vq += __shfl_xor(vq, 16); vq += __shfl_xor(vq, 32);
      s[g][f] = vs; q[g][f] = vq;
    }
  int lane = tid & 63;
  if (lane < 16) {
    int d0 = lane * 4;
    #pragma unroll
    for (int g = 0; g < 3; ++g)
      #pragma unroll
      for (int f = 0; f < 4; ++f) {
        atomicAdd(&acc[(2 * g) * 64 + d0 + f], s[g][f]);
        atomicAdd(&acc[(2 * g + 1) * 64 + d0 + f], q[g][f]);
      }
  }
  __syncthreads();
  for (int v = tid; v < 384; v += 256)
    part[(size_t)bid * 384 + v] = acc[v];
}

// ---------------------------------------------------------------------------
// Kernel B: coalesced reduce of 256 partials -> inv_std; build EHL rows
// [hi|lo] bf16, 16B chunks XOR-swizzled by row&7; pre-load out.
// Grid: 2 pairs x 256 row-tiles (32 rows each) = 512 blocks x 256 threads.
__global__ __launch_bounds__(256) void prep_kernel(
    const float* __restrict__ a, const float* __restrict__ p,
    const float* __restrict__ n, const float* __restrict__ part,
    unsigned short* __restrict__ EHL, float* __restrict__ out) {
  __shared__ float stats_s[384];
  __shared__ float is_s[64];
  int pair = blockIdx.x >> 8;
  int tb   = blockIdx.x & 255;
  int tid  = threadIdx.x;
  if (tid < 32) out[blockIdx.x * 32 + tid] = 8192.0f * EPS_OUT;
  // reduce part[b][v] over b (per-iteration coalesced; 384KB shared across blocks -> L2)
  {
    float s1 = 0.f, s2 = 0.f;
    #pragma unroll 8
    for (int b = 0; b < NPART; ++b) {
      const float* pb = part + (size_t)b * 384;
      s1 += pb[tid];
      if (tid < 128) s2 += pb[256 + tid];
    }
    stats_s[tid] = s1;
    if (tid < 128) stats_s[256 + tid] = s2;
  }
  __syncthreads();
  if (tid < 64) {
    float sa = stats_s[tid], qa = stats_s[64 + tid];
    float sb = pair ? stats_s[256 + tid] : stats_s[128 + tid];
    float qb = pair ? stats_s[320 + tid] : stats_s[192 + tid];
    const float invN = 1.0f / (float)NCO;
    float m = (sa + sb) * invN;
    float v = (qa + qb) * invN - m * m;
    is_s[tid] = 1.0f / sqrtf(v);
  }
  __syncthreads();
  const float* bptr = pair ? n : p;
  unsigned short* dst = EHL + (size_t)pair * EHL_PAIR_USHORTS;
  int c0 = tid & 7;          // chunk within row (8 bf16 = 16B)
  int rl = tid >> 3;         // row within block (0..31)
  int row = tb * 32 + rl;
  int d0 = c0 * 8;
  const float* ar = a    + (size_t)row * DFEAT + d0;
  const float* br = bptr + (size_t)row * DFEAT + d0;
  float4 a0 = *(const float4*)(ar);
  float4 a1 = *(const float4*)(ar + 4);
  float4 b0 = *(const float4*)(br);
  float4 b1 = *(const float4*)(br + 4);
  float e[8] = {a0.x - b0.x, a0.y - b0.y, a0.z - b0.z, a0.w - b0.w,
                a1.x - b1.x, a1.y - b1.y, a1.z - b1.z, a1.w - b1.w};
  u16x8 vh, vl;
  #pragma unroll
  for (int j = 0; j < 8; ++j) {
    float ej = e[j] * is_s[d0 + j];
    unsigned short hi = f2bf_rne(ej);
    vh[j] = hi;
    vl[j] = f2bf_rne(ej - bf2f(hi));
  }
  int cs = c0 ^ (row & 7);
  char* drow = (char*)dst + (size_t)row * 256;
  *(u16x8*)(drow + cs * 16)       = vh;   // hi chunk
  *(u16x8*)(drow + (8 + cs) * 16) = vl;   // lo chunk
}

// ---------------------------------------------------------------------------
// Kernel C: symmetric MFMA GEMM. Block = (pair, ib, half, squad): A tile (128
// rows) persistent in registers; tiles s = s0, s0+4, ... <= smax; per OUTER step
// stage the FULL 32KB B tile (dbuf: 2 x 32KB, A's buffer recycled), then compute
// BOTH 64-row halves (2 x 48 MFMAs) -> ONE barrier per 96 MFMAs.
// Grid: 2 x 64 x 2 x 2 = 512 blocks x 256 threads, 64KB LDS -> 2 blocks/CU.
__global__ __launch_bounds__(256, 2) void mdist_mfma(
    const unsigned short* __restrict__ EHL, float* __restrict__ out) {
  __shared__ __align__(16) unsigned char buf0[32768];  // A tile, then B ring
  __shared__ __align__(16) unsigned char buf1[32768];  // B ring
  int bid = blockIdx.x;
  int sw  = (bid & 7) * 64 + (bid >> 3);   // bijective XCD swizzle (512 = 8*64)
  int pair  = sw >> 8;
  int ib    = (sw >> 2) & 63;
  int half  = (sw >> 1) & 1;
  int squad = sw & 1;
  const char* base = (const char*)(EHL + (size_t)pair * EHL_PAIR_USHORTS);
  const char* gA = base + (size_t)ib * 32768;
  int tid = threadIdx.x;
  int s0   = half + 2 * squad;             // 0..3
  int smax = (ib < 32) ? 32 : 31;
  int nOut = (smax - s0) / 4 + 1;          // full 128-row tiles (8 or 9)

  // prologue: A -> buf0
  #pragma unroll
  for (int rr = 0; rr < 8; ++rr) {
    int off = rr * 4096 + tid * 16;
    GLOAD(gA + off, buf0 + off);
  }
  __syncthreads();

  int lane = tid & 63, w = tid >> 6;
  int wr = w >> 1, wc = w & 1;             // wave tile: rows wr*64, cols wc*32
  int l15 = lane & 15, lg = lane >> 4;

  // A fragments, resident for whole kernel: af[hk][m], hk = (half_sel<<1)|ks
  bf16x8 af[4][4];
  #pragma unroll
  for (int hk = 0; hk < 4; ++hk) {
    int c = ((hk >> 1) << 3) | ((hk & 1) << 2) | lg;
    #pragma unroll
    for (int m = 0; m < 4; ++m) {
      int rr = wr * 64 + m * 16 + l15;
      int cs = c ^ (rr & 7);
      af[hk][m] = *(const bf16x8*)(buf0 + rr * 256 + cs * 16);
    }
  }
  __syncthreads();   // all af reads done -> buf0 free for B staging

  // stage first B tile -> buf0
  {
    const char* gB0 = base + (size_t)((ib + s0) & 63) * 32768;
    #pragma unroll
    for (int rr = 0; rr < 8; ++rr) {
      int off = rr * 4096 + tid * 16;
      GLOAD(gB0 + off, buf0 + off);
    }
  }

  float rs[4][4];
  #pragma unroll
  for (int m = 0; m < 4; ++m)
    #pragma unroll
    for (int rr = 0; rr < 4; ++rr) rs[m][rr] = 0.f;

  const f32x4 zacc = {0.f, 0.f, 0.f, 0.f};
  const int AH[3] = {0, 0, 1};
  const int BH[3] = {0, 1, 0};

  for (int t = 0; t < nOut; ++t) {
    __syncthreads();   // stage(t) landed (vmcnt0 drain); reads of the other buf done
    const unsigned char* rbuf = (t & 1) ? buf1 : buf0;
    unsigned char* wbuf = (t & 1) ? buf0 : buf1;
    int s = s0 + 4 * t;
    if (t + 1 < nOut) {
      int sn = s0 + 4 * (t + 1);
      const char* gs = base + (size_t)((ib + sn) & 63) * 32768;
      #pragma unroll
      for (int rr = 0; rr < 8; ++rr) {
        int off = rr * 4096 + tid * 16;
        GLOAD(gs + off, wbuf + off);
      }
    }
    // two 64-row halves of the staged tile, 48 MFMAs each
    #pragma unroll
    for (int sub = 0; sub < 2; ++sub) {
      bf16x8 bf[4][2];
      #pragma unroll
      for (int hk = 0; hk < 4; ++hk) {
        int c = ((hk >> 1) << 3) | ((hk & 1) << 2) | lg;
        #pragma unroll
        for (int nn = 0; nn < 2; ++nn) {
          int rr = sub * 64 + wc * 32 + nn * 16 + l15;
          int cs = c ^ (rr & 7);
          bf[hk][nn] = *(const bf16x8*)(rbuf + rr * 256 + cs * 16);
        }
      }
      f32x4 acc[4][2];
      #pragma unroll
      for (int tt = 0; tt < 3; ++tt) {
        #pragma unroll
        for (int ks = 0; ks < 2; ++ks) {
          int ahk = (AH[tt] << 1) | ks;
          int bhk = (BH[tt] << 1) | ks;
          #pragma unroll
          for (int m = 0; m < 4; ++m) {
            #pragma unroll
            for (int nn = 0; nn < 2; ++nn)
              acc[m][nn] = __builtin_amdgcn_mfma_f32_16x16x32_bf16(
                  af[ahk][m], bf[bhk][nn],
                  (tt == 0 && ks == 0) ? zacc : acc[m][nn], 0, 0, 0);
          }
        }
      }
      // epilogue: f = sqrt(max(q,0)); rows always; cols for off-diag tiles
      if (s == 0) {
        #pragma unroll
        for (int m = 0; m < 4; ++m)
          #pragma unroll
          for (int nn = 0; nn < 2; ++nn)
            #pragma unroll
            for (int rr = 0; rr < 4; ++rr)
              rs[m][rr] += __builtin_amdgcn_sqrtf(fmaxf(acc[m][nn][rr], 0.f));
      } else {
        float cq0 = 0.f, cq1 = 0.f;
        #pragma unroll
        for (int m = 0; m < 4; ++m)
          #pragma unroll
          for (int nn = 0; nn < 2; ++nn)
            #pragma unroll
            for (int rr = 0; rr < 4; ++rr) {
              float f = __builtin_amdgcn_sqrtf(fmaxf(acc[m][nn][rr], 0.f));
              rs[m][rr] += f;
              if (nn == 0) cq0 += f; else cq1 += f;
            }
        cq0 += __shfl_xor(cq0, 16); cq0 += __shfl_xor(cq0, 32);
        cq1 += __shfl_xor(cq1, 16); cq1 += __shfl_xor(cq1, 32);
        if (lane < 16) {
          int jb = (ib + s) & 63;
          float* orow = &out[pair * BROWS + jb * 128 + sub * 64 + wc * 32 + l15];
          atomicAdd(orow, cq0);
          atomicAdd(orow + 16, cq1);
        }
      }
    }
  }

  // final row-sum reduce over the 16 col-lanes, one atomic per row per wave
  #pragma unroll
  for (int m = 0; m < 4; ++m)
    #pragma unroll
    for (int rr = 0; rr < 4; ++rr) {
      float v = rs[m][rr];
      v += __shfl_xor(v, 1);
      v += __shfl_xor(v, 2);
      v += __shfl_xor(v, 4);
      v += __shfl_xor(v, 8);
      rs[m][rr] = v;
    }
  if (l15 == 0) {
    int i0 = ib * 128 + wr * 64;
    #pragma unroll
    for (int m = 0; m < 4; ++m)
      #pragma unroll
      for (int rr = 0; rr < 4; ++rr)
        atomicAdd(&out[pair * BROWS + i0 + m * 16 + lg * 4 + rr], rs[m][rr]);
  }
}

// ---------------------------------------------------------------------------
extern "C" void kernel_launch(void* const* d_in, const int* in_sizes, int n_in,
                              void* d_out, int out_size, void* d_ws, size_t ws_size,
                              hipStream_t stream) {
  const float* anchor   = (const float*)d_in[0];
  const float* positive = (const float*)d_in[1];
  const float* negative = (const float*)d_in[2];
  float* out = (float*)d_out;
  float* ws  = (float*)d_ws;

  float* part = ws;
  unsigned short* EHL = (unsigned short*)(ws + WS_EHL_F);

  stats_kernel<<<256, 256, 0, stream>>>(anchor, positive, negative, part);
  prep_kernel<<<512, 256, 0, stream>>>(anchor, positive, negative, part, EHL, out);
  mdist_mfma<<<512, 256, 0, stream>>>(EHL, out);
}